// Round 3
// baseline (818.670 us; speedup 1.0000x reference)
//
#include <hip/hip_runtime.h>
#include <stdint.h>

// ---------------------------------------------------------------------------
// GAU forward on MI355X (gfx950), bf16 MFMA everywhere.
//   hid  = silu(x@Wh + bh)            -> vT [2048][8192], gate [8192][2048]
//   qk   = silu(x@Wqk + bq)           -> q,k bf16 [8192][224] (cols 200..223 zero)
//   attn = relu(q@kT / 32)^2          bf16 (full [8192][8192] if ws allows, else 2 stripes)
//   out2 = (attn@v) * gate            bf16 [8192][2048]
//   y    = (out2@Wo + bo) * x         fp32 [8192][1024]
// All GEMMs: C = A[M,K] * Bt[N,K]^T, both operands K-contiguous bf16.
// m97 structure: 128x128 tile, BK=32, 256 thr (4 waves, 2x2 of 64x64),
// global_load_lds width=16, v_mfma_f32_16x16x32_bf16.
//
// R3 change: full-M attn (grid 16x64 = 1024 blocks = 4 blocks/CU for the
// attn@v GEMM) when ws_size >= 236 MB. R2's 2-stripe path gave MODE3 only
// 512 blocks = 2 blocks/CU -> Occupancy 21.5%, 585 TF. Fallback: stripes.
// ---------------------------------------------------------------------------

typedef __bf16 bf16x8 __attribute__((ext_vector_type(8)));
typedef float f32x4 __attribute__((ext_vector_type(4)));

__device__ __forceinline__ uint16_t f2bf(float f) {
  uint32_t u = __builtin_bit_cast(uint32_t, f);
  u += 0x7fffu + ((u >> 16) & 1u);   // RNE; inputs are finite
  return (uint16_t)(u >> 16);
}
__device__ __forceinline__ float bf2f(uint16_t h) {
  uint32_t u = ((uint32_t)h) << 16;
  return __builtin_bit_cast(float, u);
}
__device__ __forceinline__ float silu_f(float s) {
  return s / (1.f + __expf(-s));
}

__device__ __forceinline__ void gload16(const void* g, void* l) {
  __builtin_amdgcn_global_load_lds(
      (__attribute__((address_space(1))) void*)const_cast<void*>(g),
      (__attribute__((address_space(3))) void*)l, 16, 0, 0);
}

// ---------------- elementwise prep ----------------

__global__ void cast_to_bf16(const float* __restrict__ in, uint16_t* __restrict__ out, int n4) {
  int i = blockIdx.x * blockDim.x + threadIdx.x;
  if (i < n4) {
    float4 f = ((const float4*)in)[i];
    ushort4 o;
    o.x = f2bf(f.x); o.y = f2bf(f.y); o.z = f2bf(f.z); o.w = f2bf(f.w);
    ((ushort4*)out)[i] = o;
  }
}

// out[c][r] = (c < C) ? (bf16)in[r][c] : 0   ; out is [Cp][R]
__global__ void transpose_cast_pad(const float* __restrict__ in, uint16_t* __restrict__ out,
                                   int R, int C, int Cp) {
  __shared__ float tile[32][33];
  int cb = blockIdx.x * 32;
  int rb = blockIdx.y * 32;
  int tx = threadIdx.x;   // 0..31
  int ty = threadIdx.y;   // 0..7
#pragma unroll
  for (int i = 0; i < 4; ++i) {
    int r = rb + ty + i * 8;
    int c = cb + tx;
    tile[ty + i * 8][tx] = (c < C) ? in[(size_t)r * C + c] : 0.f;
  }
  __syncthreads();
#pragma unroll
  for (int i = 0; i < 4; ++i) {
    int c = cb + ty + i * 8;          // out row
    if (c < Cp) out[(size_t)c * R + rb + tx] = f2bf(tile[tx][ty + i * 8]);
  }
}

// ---------------- GEMM (A * Bt^T) with fused epilogues ----------------

struct EpiParams {
  const float* bias;
  const float* g0;   // gamma[0]
  const float* b0;   // beta[0]
  const float* g1;   // gamma[1]
  const float* b1;   // beta[1]
  const uint16_t* gate;
  const float* x;
  uint16_t* o16a;
  uint16_t* o16b;
  float* o32;
};

// MODE 0: hid   (bias+silu; col<2048 -> vT[col][row], else gate[row][col-2048])
// MODE 1: qk    (bias+silu, offset-scale -> q,k [row][col], stride 224, zero pad)
// MODE 2: attn  (relu(acc/32)^2 -> attn[row][col] bf16)
// MODE 3: out2  (acc * gate -> out2g bf16)
// MODE 4: final ((acc + bias) * x -> fp32 d_out)
template <int MODE>
__global__ __launch_bounds__(256) void gemm_bt(
    const uint16_t* __restrict__ A, int lda,
    const uint16_t* __restrict__ Bt, int ldb,
    int K, EpiParams p) {
  __shared__ __align__(16) uint16_t As[128 * 32];
  __shared__ __align__(16) uint16_t Bs[128 * 32];

  const int tid = threadIdx.x;
  const int lane = tid & 63;
  const int wave = tid >> 6;
  const int wr = (wave >> 1) * 64;
  const int wc = (wave & 1) * 64;
  const int m0 = blockIdx.y * 128;
  const int n0 = blockIdx.x * 128;

  f32x4 acc[4][4] = {};

  // staging: chunk c in [0,512), row = c>>2, 16B sub-chunk = c&3. Two instrs: c = tid, 256+tid.
  const int r0 = tid >> 2;
  const int q8 = (tid & 3) * 8;
  const uint16_t* gA0 = A + (size_t)(m0 + r0) * lda + q8;
  const uint16_t* gA1 = A + (size_t)(m0 + 64 + r0) * lda + q8;
  const uint16_t* gB0 = Bt + (size_t)(n0 + r0) * ldb + q8;
  const uint16_t* gB1 = Bt + (size_t)(n0 + 64 + r0) * ldb + q8;
  uint16_t* lA0 = As + wave * 512;          // wave-uniform LDS dests (+lane*16B in HW)
  uint16_t* lA1 = As + 2048 + wave * 512;
  uint16_t* lB0 = Bs + wave * 512;
  uint16_t* lB1 = Bs + 2048 + wave * 512;

  const int fr = lane & 15;
  const int kq = (lane >> 4) * 8;

  for (int k0 = 0; k0 < K; k0 += 32) {
    __syncthreads();                       // prior compute done reading LDS
    gload16(gA0 + k0, lA0);
    gload16(gA1 + k0, lA1);
    gload16(gB0 + k0, lB0);
    gload16(gB1 + k0, lB1);
    __syncthreads();                       // vmcnt(0) drain + barrier -> tiles landed

    bf16x8 a[4], b[4];
#pragma unroll
    for (int i = 0; i < 4; ++i)
      a[i] = *(const bf16x8*)(As + (wr + i * 16 + fr) * 32 + kq);
#pragma unroll
    for (int j = 0; j < 4; ++j)
      b[j] = *(const bf16x8*)(Bs + (wc + j * 16 + fr) * 32 + kq);
#pragma unroll
    for (int i = 0; i < 4; ++i)
#pragma unroll
      for (int j = 0; j < 4; ++j)
        acc[i][j] = __builtin_amdgcn_mfma_f32_16x16x32_bf16(a[i], b[j], acc[i][j], 0, 0, 0);
  }

  // Epilogue. C/D layout: col = lane&15, row = (lane>>4)*4 + reg   [m89-verified]
#pragma unroll
  for (int i = 0; i < 4; ++i) {
#pragma unroll
    for (int j = 0; j < 4; ++j) {
      const int row = m0 + wr + i * 16 + (lane >> 4) * 4;
      const int col = n0 + wc + j * 16 + fr;

      if constexpr (MODE == 0) {
        const float bc = p.bias[col];
        if (col < 2048) {
          ushort4 o;
          float s0 = silu_f(acc[i][j][0] + bc);
          float s1 = silu_f(acc[i][j][1] + bc);
          float s2 = silu_f(acc[i][j][2] + bc);
          float s3 = silu_f(acc[i][j][3] + bc);
          o.x = f2bf(s0); o.y = f2bf(s1); o.z = f2bf(s2); o.w = f2bf(s3);
          *(ushort4*)(p.o16a + (size_t)col * 8192 + row) = o;   // vT[col][row..row+3]
        } else {
#pragma unroll
          for (int r = 0; r < 4; ++r) {
            float s = silu_f(acc[i][j][r] + bc);
            p.o16b[(size_t)(row + r) * 2048 + (col - 2048)] = f2bf(s);
          }
        }
      } else if constexpr (MODE == 1) {
        if (col < 224) {
#pragma unroll
          for (int r = 0; r < 4; ++r) {
            float qv = 0.f, kv = 0.f;
            if (col < 200) {
              float s = silu_f(acc[i][j][r] + p.bias[col]);
              qv = s * p.g0[col] + p.b0[col];
              kv = s * p.g1[col] + p.b1[col];
            }
            p.o16a[(size_t)(row + r) * 224 + col] = f2bf(qv);
            p.o16b[(size_t)(row + r) * 224 + col] = f2bf(kv);
          }
        }
      } else if constexpr (MODE == 2) {
#pragma unroll
        for (int r = 0; r < 4; ++r) {
          float s = acc[i][j][r] * 0.03125f;   // 1/sqrt(1024)
          s = fmaxf(s, 0.f);
          p.o16a[(size_t)(row + r) * 8192 + col] = f2bf(s * s);
        }
      } else if constexpr (MODE == 3) {
#pragma unroll
        for (int r = 0; r < 4; ++r) {
          float g = bf2f(p.gate[(size_t)(row + r) * 2048 + col]);
          p.o16a[(size_t)(row + r) * 2048 + col] = f2bf(acc[i][j][r] * g);
        }
      } else {  // MODE 4
        const float bc = p.bias[col];
#pragma unroll
        for (int r = 0; r < 4; ++r) {
          size_t idx = (size_t)(row + r) * 1024 + col;
          p.o32[idx] = (acc[i][j][r] + bc) * p.x[idx];
        }
      }
    }
  }
}

// ---------------- launch ----------------

extern "C" void kernel_launch(void* const* d_in, const int* in_sizes, int n_in,
                              void* d_out, int out_size, void* d_ws, size_t ws_size,
                              hipStream_t stream) {
  const float* x        = (const float*)d_in[0];
  const float* W_hidden = (const float*)d_in[1];
  const float* b_hidden = (const float*)d_in[2];
  const float* W_qk     = (const float*)d_in[3];
  const float* b_qk     = (const float*)d_in[4];
  const float* gamma    = (const float*)d_in[5];
  const float* beta     = (const float*)d_in[6];
  const float* W_out    = (const float*)d_in[7];
  const float* b_out    = (const float*)d_in[8];
  float* out = (float*)d_out;

  // Full-M path needs: attn 128 MB (region0, aliased over xb/WhT/WqkT which die
  // before attn is written) + tail 107 MB = 235 MB. Striped path: 171 MB.
  const bool fullM = ws_size >= (236ull << 20);
  const size_t region0 = fullM ? (128ull << 20) : (64ull << 20);

  char* base = (char*)d_ws;
  uint16_t* xb    = (uint16_t*)(base);                         // 16 MB  [8192][1024]
  uint16_t* WhT   = (uint16_t*)(base + (16ull << 20));         //  8 MB  [4096][1024]
  uint16_t* WqkT  = (uint16_t*)(base + (24ull << 20));         // .5 MB  [256][1024]
  uint16_t* attnB = (uint16_t*)(base);                         // 64 or 128 MB (aliases the above)
  char* tail = base + region0;
  uint16_t* WoT   = (uint16_t*)(tail);                         //  4 MB  [1024][2048]
  uint16_t* q     = (uint16_t*)(tail + (4ull << 20));          // 3.5 MB [8192][224]
  uint16_t* kk    = (uint16_t*)(tail + (4ull << 20) + 3670016);// 3.5 MB
  uint16_t* vT    = (uint16_t*)(tail + (4ull << 20) + 2 * 3670016);                  // 32 MB [2048][8192]
  uint16_t* gate  = (uint16_t*)(tail + (4ull << 20) + 2 * 3670016 + (32ull << 20));  // 32 MB
  uint16_t* out2g = (uint16_t*)(tail + (4ull << 20) + 2 * 3670016 + (64ull << 20));  // 32 MB
  (void)in_sizes; (void)n_in; (void)out_size;

  // prep
  cast_to_bf16<<<(8192 * 1024 / 4) / 256, 256, 0, stream>>>(x, xb, 8192 * 1024 / 4);
  transpose_cast_pad<<<dim3(4096 / 32, 1024 / 32), dim3(32, 8), 0, stream>>>(W_hidden, WhT, 1024, 4096, 4096);
  transpose_cast_pad<<<dim3(256 / 32, 1024 / 32), dim3(32, 8), 0, stream>>>(W_qk, WqkT, 1024, 200, 256);
  transpose_cast_pad<<<dim3(1024 / 32, 2048 / 32), dim3(32, 8), 0, stream>>>(W_out, WoT, 2048, 1024, 1024);

  // qk = silu(x@Wqk+bq) -> q,k   (N=256 logical, K=1024)
  {
    EpiParams p{};
    p.bias = b_qk; p.g0 = gamma; p.b0 = beta; p.g1 = gamma + 200; p.b1 = beta + 200;
    p.o16a = q; p.o16b = kk;
    gemm_bt<1><<<dim3(2, 64), 256, 0, stream>>>(xb, 1024, WqkT, 1024, 1024, p);
  }
  // hid = silu(x@Wh+bh) -> vT, gate   (N=4096, K=1024)
  {
    EpiParams p{};
    p.bias = b_hidden; p.o16a = vT; p.o16b = gate;
    gemm_bt<0><<<dim3(32, 64), 256, 0, stream>>>(xb, 1024, WhT, 1024, 1024, p);
  }

  if (fullM) {
    // attn = relu(q@kT/32)^2, full M   (grid 64x64)
    {
      EpiParams p{};
      p.o16a = attnB;
      gemm_bt<2><<<dim3(64, 64), 256, 0, stream>>>(q, 224, kk, 224, 224, p);
    }
    // out2g = (attn@v)*gate, full M    (grid 16x64 = 1024 blocks = 4/CU)
    {
      EpiParams p{};
      p.gate = gate; p.o16a = out2g;
      gemm_bt<3><<<dim3(16, 64), 256, 0, stream>>>(attnB, 8192, vT, 8192, 8192, p);
    }
  } else {
    for (int s = 0; s < 2; ++s) {
      {
        EpiParams p{};
        p.o16a = attnB;
        gemm_bt<2><<<dim3(64, 32), 256, 0, stream>>>(q + (size_t)s * 4096 * 224, 224, kk, 224, 224, p);
      }
      {
        EpiParams p{};
        p.gate = gate + (size_t)s * 4096 * 2048;
        p.o16a = out2g + (size_t)s * 4096 * 2048;
        gemm_bt<3><<<dim3(16, 32), 256, 0, stream>>>(attnB, 8192, vT, 8192, 8192, p);
      }
    }
  }

  // y = (out2g@Wo + bo) * x   (N=1024, K=2048)
  {
    EpiParams p{};
    p.bias = b_out; p.x = x; p.o32 = out;
    gemm_bt<4><<<dim3(8, 64), 256, 0, stream>>>(out2g, 2048, WoT, 2048, 2048, p);
  }
}

// Round 4
// 668.581 us; speedup vs baseline: 1.2245x; 1.2245x over previous
//
#include <hip/hip_runtime.h>
#include <stdint.h>

// ---------------------------------------------------------------------------
// GAU forward on MI355X (gfx950), bf16 MFMA everywhere.
//   hid  = silu(x@Wh + bh)            -> vT [2048][8192], gate [8192][2048]
//   qk   = silu(x@Wqk + bq)           -> q,k bf16 [8192][224] (cols 200..223 zero)
//   attn = relu(q@kT / 32)^2          bf16 (full [8192][8192] if ws allows, else 2 stripes)
//   out2 = (attn@v) * gate            bf16 [8192][2048]   <-- R4: wide-tile kernel
//   y    = (out2@Wo + bo) * x         fp32 [8192][1024]
//
// R4 change: MODE3 (attn@v) uses a 128x256 tile / 512-thread kernel with an
// XCD swizzle (panel-sharing blocks -> same XCD). R3 showed occupancy was not
// the limiter; FETCH 695 MB (ideal 192) says attn panel re-reads miss cache.
// TileN 256 halves attn logical re-reads; swizzle localizes them to one L2.
// ---------------------------------------------------------------------------

typedef __bf16 bf16x8 __attribute__((ext_vector_type(8)));
typedef float f32x4 __attribute__((ext_vector_type(4)));

__device__ __forceinline__ uint16_t f2bf(float f) {
  uint32_t u = __builtin_bit_cast(uint32_t, f);
  u += 0x7fffu + ((u >> 16) & 1u);   // RNE; inputs are finite
  return (uint16_t)(u >> 16);
}
__device__ __forceinline__ float bf2f(uint16_t h) {
  uint32_t u = ((uint32_t)h) << 16;
  return __builtin_bit_cast(float, u);
}
__device__ __forceinline__ float silu_f(float s) {
  return s / (1.f + __expf(-s));
}

__device__ __forceinline__ void gload16(const void* g, void* l) {
  __builtin_amdgcn_global_load_lds(
      (__attribute__((address_space(1))) void*)const_cast<void*>(g),
      (__attribute__((address_space(3))) void*)l, 16, 0, 0);
}

// ---------------- elementwise prep ----------------

__global__ void cast_to_bf16(const float* __restrict__ in, uint16_t* __restrict__ out, int n4) {
  int i = blockIdx.x * blockDim.x + threadIdx.x;
  if (i < n4) {
    float4 f = ((const float4*)in)[i];
    ushort4 o;
    o.x = f2bf(f.x); o.y = f2bf(f.y); o.z = f2bf(f.z); o.w = f2bf(f.w);
    ((ushort4*)out)[i] = o;
  }
}

// out[c][r] = (c < C) ? (bf16)in[r][c] : 0   ; out is [Cp][R]
__global__ void transpose_cast_pad(const float* __restrict__ in, uint16_t* __restrict__ out,
                                   int R, int C, int Cp) {
  __shared__ float tile[32][33];
  int cb = blockIdx.x * 32;
  int rb = blockIdx.y * 32;
  int tx = threadIdx.x;   // 0..31
  int ty = threadIdx.y;   // 0..7
#pragma unroll
  for (int i = 0; i < 4; ++i) {
    int r = rb + ty + i * 8;
    int c = cb + tx;
    tile[ty + i * 8][tx] = (c < C) ? in[(size_t)r * C + c] : 0.f;
  }
  __syncthreads();
#pragma unroll
  for (int i = 0; i < 4; ++i) {
    int c = cb + ty + i * 8;          // out row
    if (c < Cp) out[(size_t)c * R + rb + tx] = f2bf(tile[tx][ty + i * 8]);
  }
}

// ---------------- GEMM (A * Bt^T) with fused epilogues ----------------

struct EpiParams {
  const float* bias;
  const float* g0;   // gamma[0]
  const float* b0;   // beta[0]
  const float* g1;   // gamma[1]
  const float* b1;   // beta[1]
  const uint16_t* gate;
  const float* x;
  uint16_t* o16a;
  uint16_t* o16b;
  float* o32;
};

// MODE 0: hid   (bias+silu; col<2048 -> vT[col][row], else gate[row][col-2048])
// MODE 1: qk    (bias+silu, offset-scale -> q,k [row][col], stride 224, zero pad)
// MODE 2: attn  (relu(acc/32)^2 -> attn[row][col] bf16)
// MODE 4: final ((acc + bias) * x -> fp32 d_out)
template <int MODE>
__global__ __launch_bounds__(256) void gemm_bt(
    const uint16_t* __restrict__ A, int lda,
    const uint16_t* __restrict__ Bt, int ldb,
    int K, EpiParams p) {
  __shared__ __align__(16) uint16_t As[128 * 32];
  __shared__ __align__(16) uint16_t Bs[128 * 32];

  const int tid = threadIdx.x;
  const int lane = tid & 63;
  const int wave = tid >> 6;
  const int wr = (wave >> 1) * 64;
  const int wc = (wave & 1) * 64;
  const int m0 = blockIdx.y * 128;
  const int n0 = blockIdx.x * 128;

  f32x4 acc[4][4] = {};

  const int r0 = tid >> 2;
  const int q8 = (tid & 3) * 8;
  const uint16_t* gA0 = A + (size_t)(m0 + r0) * lda + q8;
  const uint16_t* gA1 = A + (size_t)(m0 + 64 + r0) * lda + q8;
  const uint16_t* gB0 = Bt + (size_t)(n0 + r0) * ldb + q8;
  const uint16_t* gB1 = Bt + (size_t)(n0 + 64 + r0) * ldb + q8;
  uint16_t* lA0 = As + wave * 512;          // wave-uniform LDS dests (+lane*16B in HW)
  uint16_t* lA1 = As + 2048 + wave * 512;
  uint16_t* lB0 = Bs + wave * 512;
  uint16_t* lB1 = Bs + 2048 + wave * 512;

  const int fr = lane & 15;
  const int kq = (lane >> 4) * 8;

  for (int k0 = 0; k0 < K; k0 += 32) {
    __syncthreads();
    gload16(gA0 + k0, lA0);
    gload16(gA1 + k0, lA1);
    gload16(gB0 + k0, lB0);
    gload16(gB1 + k0, lB1);
    __syncthreads();

    bf16x8 a[4], b[4];
#pragma unroll
    for (int i = 0; i < 4; ++i)
      a[i] = *(const bf16x8*)(As + (wr + i * 16 + fr) * 32 + kq);
#pragma unroll
    for (int j = 0; j < 4; ++j)
      b[j] = *(const bf16x8*)(Bs + (wc + j * 16 + fr) * 32 + kq);
#pragma unroll
    for (int i = 0; i < 4; ++i)
#pragma unroll
      for (int j = 0; j < 4; ++j)
        acc[i][j] = __builtin_amdgcn_mfma_f32_16x16x32_bf16(a[i], b[j], acc[i][j], 0, 0, 0);
  }

  // Epilogue. C/D layout: col = lane&15, row = (lane>>4)*4 + reg   [m89-verified]
#pragma unroll
  for (int i = 0; i < 4; ++i) {
#pragma unroll
    for (int j = 0; j < 4; ++j) {
      const int row = m0 + wr + i * 16 + (lane >> 4) * 4;
      const int col = n0 + wc + j * 16 + fr;

      if constexpr (MODE == 0) {
        const float bc = p.bias[col];
        if (col < 2048) {
          ushort4 o;
          float s0 = silu_f(acc[i][j][0] + bc);
          float s1 = silu_f(acc[i][j][1] + bc);
          float s2 = silu_f(acc[i][j][2] + bc);
          float s3 = silu_f(acc[i][j][3] + bc);
          o.x = f2bf(s0); o.y = f2bf(s1); o.z = f2bf(s2); o.w = f2bf(s3);
          *(ushort4*)(p.o16a + (size_t)col * 8192 + row) = o;   // vT[col][row..row+3]
        } else {
#pragma unroll
          for (int r = 0; r < 4; ++r) {
            float s = silu_f(acc[i][j][r] + bc);
            p.o16b[(size_t)(row + r) * 2048 + (col - 2048)] = f2bf(s);
          }
        }
      } else if constexpr (MODE == 1) {
        if (col < 224) {
#pragma unroll
          for (int r = 0; r < 4; ++r) {
            float qv = 0.f, kv = 0.f;
            if (col < 200) {
              float s = silu_f(acc[i][j][r] + p.bias[col]);
              qv = s * p.g0[col] + p.b0[col];
              kv = s * p.g1[col] + p.b1[col];
            }
            p.o16a[(size_t)(row + r) * 224 + col] = f2bf(qv);
            p.o16b[(size_t)(row + r) * 224 + col] = f2bf(kv);
          }
        }
      } else if constexpr (MODE == 2) {
#pragma unroll
        for (int r = 0; r < 4; ++r) {
          float s = acc[i][j][r] * 0.03125f;   // 1/sqrt(1024)
          s = fmaxf(s, 0.f);
          p.o16a[(size_t)(row + r) * 8192 + col] = f2bf(s * s);
        }
      } else {  // MODE 4
        const float bc = p.bias[col];
#pragma unroll
        for (int r = 0; r < 4; ++r) {
          size_t idx = (size_t)(row + r) * 1024 + col;
          p.o32[idx] = (acc[i][j][r] + bc) * p.x[idx];
        }
      }
    }
  }
}

// MODE3 wide: 128(M) x 256(N) tile, 512 threads = 8 waves (2 rows x 4 cols of
// 64x64 wave-tiles). XCD swizzle: flat grid; blocks sharing an attn m-panel
// (same y, all nx x-tiles) get ids congruent mod 8 -> same XCD's L2.
__global__ __launch_bounds__(512) void gemm_wide3(
    const uint16_t* __restrict__ A, int lda,
    const uint16_t* __restrict__ Bt, int ldb,
    int K, int nx, EpiParams p) {
  __shared__ __align__(16) uint16_t As[128 * 32];   //  8 KB
  __shared__ __align__(16) uint16_t Bs[256 * 32];   // 16 KB

  const int id = blockIdx.x;
  const int bx = (id >> 3) % nx;              // n-tile
  const int by = (id & 7) + 8 * (id / (8 * nx));  // m-tile
  const int m0 = by * 128;
  const int n0 = bx * 256;

  const int tid = threadIdx.x;
  const int lane = tid & 63;
  const int wave = tid >> 6;
  const int wr = (wave & 1) * 64;
  const int wc = (wave >> 1) * 64;

  f32x4 acc[4][4] = {};

  const int r0 = tid >> 2;                    // 0..127
  const int q8 = (tid & 3) * 8;
  const uint16_t* gA  = A  + (size_t)(m0 + r0) * lda + q8;
  const uint16_t* gB0 = Bt + (size_t)(n0 + r0) * ldb + q8;
  const uint16_t* gB1 = Bt + (size_t)(n0 + 128 + r0) * ldb + q8;
  uint16_t* lA  = As + wave * 512;
  uint16_t* lB0 = Bs + wave * 512;
  uint16_t* lB1 = Bs + 4096 + wave * 512;

  const int fr = lane & 15;
  const int kq = (lane >> 4) * 8;

  for (int k0 = 0; k0 < K; k0 += 32) {
    __syncthreads();
    gload16(gA + k0, lA);
    gload16(gB0 + k0, lB0);
    gload16(gB1 + k0, lB1);
    __syncthreads();

    bf16x8 a[4], b[4];
#pragma unroll
    for (int i = 0; i < 4; ++i)
      a[i] = *(const bf16x8*)(As + (wr + i * 16 + fr) * 32 + kq);
#pragma unroll
    for (int j = 0; j < 4; ++j)
      b[j] = *(const bf16x8*)(Bs + (wc + j * 16 + fr) * 32 + kq);
#pragma unroll
    for (int i = 0; i < 4; ++i)
#pragma unroll
      for (int j = 0; j < 4; ++j)
        acc[i][j] = __builtin_amdgcn_mfma_f32_16x16x32_bf16(a[i], b[j], acc[i][j], 0, 0, 0);
  }

#pragma unroll
  for (int i = 0; i < 4; ++i) {
#pragma unroll
    for (int j = 0; j < 4; ++j) {
      const int row = m0 + wr + i * 16 + (lane >> 4) * 4;
      const int col = n0 + wc + j * 16 + fr;
#pragma unroll
      for (int r = 0; r < 4; ++r) {
        float g = bf2f(p.gate[(size_t)(row + r) * 2048 + col]);
        p.o16a[(size_t)(row + r) * 2048 + col] = f2bf(acc[i][j][r] * g);
      }
    }
  }
}

// ---------------- launch ----------------

extern "C" void kernel_launch(void* const* d_in, const int* in_sizes, int n_in,
                              void* d_out, int out_size, void* d_ws, size_t ws_size,
                              hipStream_t stream) {
  const float* x        = (const float*)d_in[0];
  const float* W_hidden = (const float*)d_in[1];
  const float* b_hidden = (const float*)d_in[2];
  const float* W_qk     = (const float*)d_in[3];
  const float* b_qk     = (const float*)d_in[4];
  const float* gamma    = (const float*)d_in[5];
  const float* beta     = (const float*)d_in[6];
  const float* W_out    = (const float*)d_in[7];
  const float* b_out    = (const float*)d_in[8];
  float* out = (float*)d_out;

  const bool fullM = ws_size >= (236ull << 20);
  const size_t region0 = fullM ? (128ull << 20) : (64ull << 20);

  char* base = (char*)d_ws;
  uint16_t* xb    = (uint16_t*)(base);                         // 16 MB  [8192][1024]
  uint16_t* WhT   = (uint16_t*)(base + (16ull << 20));         //  8 MB  [4096][1024]
  uint16_t* WqkT  = (uint16_t*)(base + (24ull << 20));         // .5 MB  [256][1024]
  uint16_t* attnB = (uint16_t*)(base);                         // 64/128 MB (aliases the above)
  char* tail = base + region0;
  uint16_t* WoT   = (uint16_t*)(tail);                         //  4 MB  [1024][2048]
  uint16_t* q     = (uint16_t*)(tail + (4ull << 20));          // 3.5 MB [8192][224]
  uint16_t* kk    = (uint16_t*)(tail + (4ull << 20) + 3670016);// 3.5 MB
  uint16_t* vT    = (uint16_t*)(tail + (4ull << 20) + 2 * 3670016);                  // 32 MB [2048][8192]
  uint16_t* gate  = (uint16_t*)(tail + (4ull << 20) + 2 * 3670016 + (32ull << 20));  // 32 MB
  uint16_t* out2g = (uint16_t*)(tail + (4ull << 20) + 2 * 3670016 + (64ull << 20));  // 32 MB
  (void)in_sizes; (void)n_in; (void)out_size;

  // prep
  cast_to_bf16<<<(8192 * 1024 / 4) / 256, 256, 0, stream>>>(x, xb, 8192 * 1024 / 4);
  transpose_cast_pad<<<dim3(4096 / 32, 1024 / 32), dim3(32, 8), 0, stream>>>(W_hidden, WhT, 1024, 4096, 4096);
  transpose_cast_pad<<<dim3(256 / 32, 1024 / 32), dim3(32, 8), 0, stream>>>(W_qk, WqkT, 1024, 200, 256);
  transpose_cast_pad<<<dim3(1024 / 32, 2048 / 32), dim3(32, 8), 0, stream>>>(W_out, WoT, 2048, 1024, 1024);

  // qk = silu(x@Wqk+bq) -> q,k
  {
    EpiParams p{};
    p.bias = b_qk; p.g0 = gamma; p.b0 = beta; p.g1 = gamma + 200; p.b1 = beta + 200;
    p.o16a = q; p.o16b = kk;
    gemm_bt<1><<<dim3(2, 64), 256, 0, stream>>>(xb, 1024, WqkT, 1024, 1024, p);
  }
  // hid = silu(x@Wh+bh) -> vT, gate
  {
    EpiParams p{};
    p.bias = b_hidden; p.o16a = vT; p.o16b = gate;
    gemm_bt<0><<<dim3(32, 64), 256, 0, stream>>>(xb, 1024, WhT, 1024, 1024, p);
  }

  if (fullM) {
    {
      EpiParams p{};
      p.o16a = attnB;
      gemm_bt<2><<<dim3(64, 64), 256, 0, stream>>>(q, 224, kk, 224, 224, p);
    }
    {
      EpiParams p{};
      p.gate = gate; p.o16a = out2g;
      gemm_wide3<<<dim3(8 * 64), 512, 0, stream>>>(attnB, 8192, vT, 8192, 8192, 8, p);
    }
  } else {
    for (int s = 0; s < 2; ++s) {
      {
        EpiParams p{};
        p.o16a = attnB;
        gemm_bt<2><<<dim3(64, 32), 256, 0, stream>>>(q + (size_t)s * 4096 * 224, 224, kk, 224, 224, p);
      }
      {
        EpiParams p{};
        p.gate = gate + (size_t)s * 4096 * 2048;
        p.o16a = out2g + (size_t)s * 4096 * 2048;
        gemm_wide3<<<dim3(8 * 32), 512, 0, stream>>>(attnB, 8192, vT, 8192, 8192, 8, p);
      }
    }
  }

  // y = (out2g@Wo + bo) * x
  {
    EpiParams p{};
    p.bias = b_out; p.x = x; p.o32 = out;
    gemm_bt<4><<<dim3(8, 64), 256, 0, stream>>>(out2g, 2048, WoT, 2048, 2048, p);
  }
}

// Round 5
// 668.065 us; speedup vs baseline: 1.2254x; 1.0008x over previous
//
#include <hip/hip_runtime.h>
#include <stdint.h>

// ---------------------------------------------------------------------------
// GAU forward on MI355X (gfx950), bf16 MFMA everywhere.
//   fused: [hid|qk] = silu(x@[Wh|Wqk] + b)  -> vT [2048][8192], gate [8192][2048],
//                                              q,k bf16 [8192][224] (cols 200.. zero)
//   attn = relu(q@kT / 32)^2          bf16 (full [8192][8192] if ws allows, else 2 stripes)
//   out2 = (attn@v) * gate            bf16 [8192][2048]   (k_pv, 128x256 tile, XCD swizzle)
//   y    = (out2@Wo + bo) * x         fp32 [8192][1024]
//
// R5: (1) distinct kernel names per stage for profiling; (2) qk GEMM merged
// into hid GEMM (N=4352; standalone qk had 128 blocks = grid-starved);
// (3) k_attn epilogue bounces each wave's 16x64 subtile through private LDS
// (double-buffered, no barriers) -> 16B/lane coalesced stores instead of 2B.
// k_pv is at the m97-structure plateau (890 TF) -- left untouched.
// ---------------------------------------------------------------------------

typedef __bf16 bf16x8 __attribute__((ext_vector_type(8)));
typedef float f32x4 __attribute__((ext_vector_type(4)));

__device__ __forceinline__ uint16_t f2bf(float f) {
  uint32_t u = __builtin_bit_cast(uint32_t, f);
  u += 0x7fffu + ((u >> 16) & 1u);   // RNE; inputs are finite
  return (uint16_t)(u >> 16);
}
__device__ __forceinline__ float bf2f(uint16_t h) {
  uint32_t u = ((uint32_t)h) << 16;
  return __builtin_bit_cast(float, u);
}
__device__ __forceinline__ float silu_f(float s) {
  return s / (1.f + __expf(-s));
}

__device__ __forceinline__ void gload16(const void* g, void* l) {
  __builtin_amdgcn_global_load_lds(
      (__attribute__((address_space(1))) void*)const_cast<void*>(g),
      (__attribute__((address_space(3))) void*)l, 16, 0, 0);
}

// ---------------- elementwise prep ----------------

__global__ void cast_to_bf16(const float* __restrict__ in, uint16_t* __restrict__ out, int n4) {
  int i = blockIdx.x * blockDim.x + threadIdx.x;
  if (i < n4) {
    float4 f = ((const float4*)in)[i];
    ushort4 o;
    o.x = f2bf(f.x); o.y = f2bf(f.y); o.z = f2bf(f.z); o.w = f2bf(f.w);
    ((ushort4*)out)[i] = o;
  }
}

// out[c][r] = (c < C) ? (bf16)in[r][c] : 0   ; out is [Cp][R]
__global__ void transpose_cast_pad(const float* __restrict__ in, uint16_t* __restrict__ out,
                                   int R, int C, int Cp) {
  __shared__ float tile[32][33];
  int cb = blockIdx.x * 32;
  int rb = blockIdx.y * 32;
  int tx = threadIdx.x;   // 0..31
  int ty = threadIdx.y;   // 0..7
#pragma unroll
  for (int i = 0; i < 4; ++i) {
    int r = rb + ty + i * 8;
    int c = cb + tx;
    tile[ty + i * 8][tx] = (c < C) ? in[(size_t)r * C + c] : 0.f;
  }
  __syncthreads();
#pragma unroll
  for (int i = 0; i < 4; ++i) {
    int c = cb + ty + i * 8;          // out row
    if (c < Cp) out[(size_t)c * R + rb + tx] = f2bf(tile[tx][ty + i * 8]);
  }
}

// ---------------- params ----------------

struct EpiParams {
  const float* bias;    // b_hidden (fused) / b_out (final)
  const float* bias2;   // b_qk
  const float* g0;
  const float* b0;
  const float* g1;
  const float* b1;
  const uint16_t* gate;
  const float* x;
  uint16_t* o16a;       // vT / attn / out2g
  uint16_t* o16b;       // gate
  uint16_t* oq;
  uint16_t* ok;
  float* o32;
};

// ---------------------------------------------------------------------------
// k_fused_hid_qk: C = xb[8192,1024] @ [WhT;WqkT][4352,1024]^T, 128x128 tile.
// col <2048 -> vT (silu); <4096 -> gate (silu); <4296 -> q/k (silu+affine);
// 4296..4319 -> zero-pad q/k; rest ignored.
// ---------------------------------------------------------------------------
__global__ __launch_bounds__(256) void k_fused_hid_qk(
    const uint16_t* __restrict__ A, const uint16_t* __restrict__ Bt, EpiParams p) {
  __shared__ __align__(16) uint16_t As[128 * 32];
  __shared__ __align__(16) uint16_t Bs[128 * 32];

  const int tid = threadIdx.x;
  const int lane = tid & 63;
  const int wave = tid >> 6;
  const int wr = (wave >> 1) * 64;
  const int wc = (wave & 1) * 64;
  const int m0 = blockIdx.y * 128;
  const int n0 = blockIdx.x * 128;
  const int lda = 1024, ldb = 1024, K = 1024;

  f32x4 acc[4][4] = {};

  const int r0 = tid >> 2;
  const int q8 = (tid & 3) * 8;
  const uint16_t* gA0 = A + (size_t)(m0 + r0) * lda + q8;
  const uint16_t* gA1 = A + (size_t)(m0 + 64 + r0) * lda + q8;
  const uint16_t* gB0 = Bt + (size_t)(n0 + r0) * ldb + q8;
  const uint16_t* gB1 = Bt + (size_t)(n0 + 64 + r0) * ldb + q8;
  uint16_t* lA0 = As + wave * 512;
  uint16_t* lA1 = As + 2048 + wave * 512;
  uint16_t* lB0 = Bs + wave * 512;
  uint16_t* lB1 = Bs + 2048 + wave * 512;

  const int fr = lane & 15;
  const int kq = (lane >> 4) * 8;

  for (int k0 = 0; k0 < K; k0 += 32) {
    __syncthreads();
    gload16(gA0 + k0, lA0);
    gload16(gA1 + k0, lA1);
    gload16(gB0 + k0, lB0);
    gload16(gB1 + k0, lB1);
    __syncthreads();

    bf16x8 a[4], b[4];
#pragma unroll
    for (int i = 0; i < 4; ++i)
      a[i] = *(const bf16x8*)(As + (wr + i * 16 + fr) * 32 + kq);
#pragma unroll
    for (int j = 0; j < 4; ++j)
      b[j] = *(const bf16x8*)(Bs + (wc + j * 16 + fr) * 32 + kq);
#pragma unroll
    for (int i = 0; i < 4; ++i)
#pragma unroll
      for (int j = 0; j < 4; ++j)
        acc[i][j] = __builtin_amdgcn_mfma_f32_16x16x32_bf16(a[i], b[j], acc[i][j], 0, 0, 0);
  }

#pragma unroll
  for (int i = 0; i < 4; ++i) {
#pragma unroll
    for (int j = 0; j < 4; ++j) {
      const int row = m0 + wr + i * 16 + (lane >> 4) * 4;
      const int col = n0 + wc + j * 16 + fr;

      if (col < 2048) {                       // vT (silu), transposed store
        const float bc = p.bias[col];
        ushort4 o;
        o.x = f2bf(silu_f(acc[i][j][0] + bc));
        o.y = f2bf(silu_f(acc[i][j][1] + bc));
        o.z = f2bf(silu_f(acc[i][j][2] + bc));
        o.w = f2bf(silu_f(acc[i][j][3] + bc));
        *(ushort4*)(p.o16a + (size_t)col * 8192 + row) = o;
      } else if (col < 4096) {                // gate (silu)
        const float bc = p.bias[col];
#pragma unroll
        for (int r = 0; r < 4; ++r)
          p.o16b[(size_t)(row + r) * 2048 + (col - 2048)] = f2bf(silu_f(acc[i][j][r] + bc));
      } else {                                // q,k
        const int qc = col - 4096;
        if (qc < 224) {
#pragma unroll
          for (int r = 0; r < 4; ++r) {
            float qv = 0.f, kv = 0.f;
            if (qc < 200) {
              float s = silu_f(acc[i][j][r] + p.bias2[qc]);
              qv = s * p.g0[qc] + p.b0[qc];
              kv = s * p.g1[qc] + p.b1[qc];
            }
            p.oq[(size_t)(row + r) * 224 + qc] = f2bf(qv);
            p.ok[(size_t)(row + r) * 224 + qc] = f2bf(kv);
          }
        }
      }
    }
  }
}

// ---------------------------------------------------------------------------
// k_attn: attn = relu(q@kT / 32)^2, K=224, 128x128 tile.
// Epilogue bounces each wave's 16x64 subtile through a private LDS arena
// (double-buffered), then stores 2x16B per lane (coalesced 128B-line rows).
// ---------------------------------------------------------------------------
__global__ __launch_bounds__(256) void k_attn(
    const uint16_t* __restrict__ A,
    const uint16_t* __restrict__ Bt, EpiParams p) {
  __shared__ __align__(16) uint16_t As[128 * 32];
  __shared__ __align__(16) uint16_t Bs[128 * 32];
  __shared__ __align__(16) uint16_t Ep[4][2][16 * 72];   // 18.4 KB, per-wave dbuf

  const int tid = threadIdx.x;
  const int lane = tid & 63;
  const int wave = tid >> 6;
  const int wr = (wave >> 1) * 64;
  const int wc = (wave & 1) * 64;
  const int m0 = blockIdx.y * 128;
  const int n0 = blockIdx.x * 128;
  const int lda = 224, ldb = 224, K = 224;

  f32x4 acc[4][4] = {};

  const int r0 = tid >> 2;
  const int q8 = (tid & 3) * 8;
  const uint16_t* gA0 = A + (size_t)(m0 + r0) * lda + q8;
  const uint16_t* gA1 = A + (size_t)(m0 + 64 + r0) * lda + q8;
  const uint16_t* gB0 = Bt + (size_t)(n0 + r0) * ldb + q8;
  const uint16_t* gB1 = Bt + (size_t)(n0 + 64 + r0) * ldb + q8;
  uint16_t* lA0 = As + wave * 512;
  uint16_t* lA1 = As + 2048 + wave * 512;
  uint16_t* lB0 = Bs + wave * 512;
  uint16_t* lB1 = Bs + 2048 + wave * 512;

  const int fr = lane & 15;
  const int kq = (lane >> 4) * 8;

  for (int k0 = 0; k0 < K; k0 += 32) {
    __syncthreads();
    gload16(gA0 + k0, lA0);
    gload16(gA1 + k0, lA1);
    gload16(gB0 + k0, lB0);
    gload16(gB1 + k0, lB1);
    __syncthreads();

    bf16x8 a[4], b[4];
#pragma unroll
    for (int i = 0; i < 4; ++i)
      a[i] = *(const bf16x8*)(As + (wr + i * 16 + fr) * 32 + kq);
#pragma unroll
    for (int j = 0; j < 4; ++j)
      b[j] = *(const bf16x8*)(Bs + (wc + j * 16 + fr) * 32 + kq);
#pragma unroll
    for (int i = 0; i < 4; ++i)
#pragma unroll
      for (int j = 0; j < 4; ++j)
        acc[i][j] = __builtin_amdgcn_mfma_f32_16x16x32_bf16(a[i], b[j], acc[i][j], 0, 0, 0);
  }

  // LDS-bounce epilogue: per i, wave-local [16 rows][64 cols], stride 72
  // (144 B rows: 16B-aligned reads, banks spread for writes).
#pragma unroll
  for (int i = 0; i < 4; ++i) {
    uint16_t* sl = Ep[wave][i & 1];
#pragma unroll
    for (int j = 0; j < 4; ++j) {
#pragma unroll
      for (int r = 0; r < 4; ++r) {
        float s = fmaxf(acc[i][j][r] * 0.03125f, 0.f);
        sl[((lane >> 4) * 4 + r) * 72 + j * 16 + fr] = f2bf(s * s);
      }
    }
    const int row = lane >> 2;          // 0..15
    const int c0 = (lane & 3) * 16;     // 0,16,32,48
    bf16x8 v0 = *(const bf16x8*)(sl + row * 72 + c0);
    bf16x8 v1 = *(const bf16x8*)(sl + row * 72 + c0 + 8);
    uint16_t* dst = p.o16a + (size_t)(m0 + wr + i * 16 + row) * 8192 + (n0 + wc + c0);
    *(bf16x8*)(dst) = v0;
    *(bf16x8*)(dst + 8) = v1;
  }
}

// ---------------------------------------------------------------------------
// k_pv: out2 = (attn@v)*gate. 128(M) x 256(N) tile, 512 thr = 8 waves.
// XCD swizzle: blocks sharing an attn m-panel get ids congruent mod 8.
// At the m97-structure plateau (890 TF) -- structure frozen.
// ---------------------------------------------------------------------------
__global__ __launch_bounds__(512) void k_pv(
    const uint16_t* __restrict__ A, int lda,
    const uint16_t* __restrict__ Bt, int ldb,
    int K, int nx, EpiParams p) {
  __shared__ __align__(16) uint16_t As[128 * 32];   //  8 KB
  __shared__ __align__(16) uint16_t Bs[256 * 32];   // 16 KB

  const int id = blockIdx.x;
  const int bx = (id >> 3) % nx;
  const int by = (id & 7) + 8 * (id / (8 * nx));
  const int m0 = by * 128;
  const int n0 = bx * 256;

  const int tid = threadIdx.x;
  const int lane = tid & 63;
  const int wave = tid >> 6;
  const int wr = (wave & 1) * 64;
  const int wc = (wave >> 1) * 64;

  f32x4 acc[4][4] = {};

  const int r0 = tid >> 2;                    // 0..127
  const int q8 = (tid & 3) * 8;
  const uint16_t* gA  = A  + (size_t)(m0 + r0) * lda + q8;
  const uint16_t* gB0 = Bt + (size_t)(n0 + r0) * ldb + q8;
  const uint16_t* gB1 = Bt + (size_t)(n0 + 128 + r0) * ldb + q8;
  uint16_t* lA  = As + wave * 512;
  uint16_t* lB0 = Bs + wave * 512;
  uint16_t* lB1 = Bs + 4096 + wave * 512;

  const int fr = lane & 15;
  const int kq = (lane >> 4) * 8;

  for (int k0 = 0; k0 < K; k0 += 32) {
    __syncthreads();
    gload16(gA + k0, lA);
    gload16(gB0 + k0, lB0);
    gload16(gB1 + k0, lB1);
    __syncthreads();

    bf16x8 a[4], b[4];
#pragma unroll
    for (int i = 0; i < 4; ++i)
      a[i] = *(const bf16x8*)(As + (wr + i * 16 + fr) * 32 + kq);
#pragma unroll
    for (int j = 0; j < 4; ++j)
      b[j] = *(const bf16x8*)(Bs + (wc + j * 16 + fr) * 32 + kq);
#pragma unroll
    for (int i = 0; i < 4; ++i)
#pragma unroll
      for (int j = 0; j < 4; ++j)
        acc[i][j] = __builtin_amdgcn_mfma_f32_16x16x32_bf16(a[i], b[j], acc[i][j], 0, 0, 0);
  }

#pragma unroll
  for (int i = 0; i < 4; ++i) {
#pragma unroll
    for (int j = 0; j < 4; ++j) {
      const int row = m0 + wr + i * 16 + (lane >> 4) * 4;
      const int col = n0 + wc + j * 16 + fr;
#pragma unroll
      for (int r = 0; r < 4; ++r) {
        float g = bf2f(p.gate[(size_t)(row + r) * 2048 + col]);
        p.o16a[(size_t)(row + r) * 2048 + col] = f2bf(acc[i][j][r] * g);
      }
    }
  }
}

// ---------------------------------------------------------------------------
// k_final: y = (out2g@WoT^T + bo) * x, fp32 out. 128x128 tile, K=2048.
// ---------------------------------------------------------------------------
__global__ __launch_bounds__(256) void k_final(
    const uint16_t* __restrict__ A,
    const uint16_t* __restrict__ Bt, EpiParams p) {
  __shared__ __align__(16) uint16_t As[128 * 32];
  __shared__ __align__(16) uint16_t Bs[128 * 32];

  const int tid = threadIdx.x;
  const int lane = tid & 63;
  const int wave = tid >> 6;
  const int wr = (wave >> 1) * 64;
  const int wc = (wave & 1) * 64;
  const int m0 = blockIdx.y * 128;
  const int n0 = blockIdx.x * 128;
  const int lda = 2048, ldb = 2048, K = 2048;

  f32x4 acc[4][4] = {};

  const int r0 = tid >> 2;
  const int q8 = (tid & 3) * 8;
  const uint16_t* gA0 = A + (size_t)(m0 + r0) * lda + q8;
  const uint16_t* gA1 = A + (size_t)(m0 + 64 + r0) * lda + q8;
  const uint16_t* gB0 = Bt + (size_t)(n0 + r0) * ldb + q8;
  const uint16_t* gB1 = Bt + (size_t)(n0 + 64 + r0) * ldb + q8;
  uint16_t* lA0 = As + wave * 512;
  uint16_t* lA1 = As + 2048 + wave * 512;
  uint16_t* lB0 = Bs + wave * 512;
  uint16_t* lB1 = Bs + 2048 + wave * 512;

  const int fr = lane & 15;
  const int kq = (lane >> 4) * 8;

  for (int k0 = 0; k0 < K; k0 += 32) {
    __syncthreads();
    gload16(gA0 + k0, lA0);
    gload16(gA1 + k0, lA1);
    gload16(gB0 + k0, lB0);
    gload16(gB1 + k0, lB1);
    __syncthreads();

    bf16x8 a[4], b[4];
#pragma unroll
    for (int i = 0; i < 4; ++i)
      a[i] = *(const bf16x8*)(As + (wr + i * 16 + fr) * 32 + kq);
#pragma unroll
    for (int j = 0; j < 4; ++j)
      b[j] = *(const bf16x8*)(Bs + (wc + j * 16 + fr) * 32 + kq);
#pragma unroll
    for (int i = 0; i < 4; ++i)
#pragma unroll
      for (int j = 0; j < 4; ++j)
        acc[i][j] = __builtin_amdgcn_mfma_f32_16x16x32_bf16(a[i], b[j], acc[i][j], 0, 0, 0);
  }

#pragma unroll
  for (int i = 0; i < 4; ++i) {
#pragma unroll
    for (int j = 0; j < 4; ++j) {
      const int row = m0 + wr + i * 16 + (lane >> 4) * 4;
      const int col = n0 + wc + j * 16 + fr;
      const float bc = p.bias[col];
#pragma unroll
      for (int r = 0; r < 4; ++r) {
        size_t idx = (size_t)(row + r) * 1024 + col;
        p.o32[idx] = (acc[i][j][r] + bc) * p.x[idx];
      }
    }
  }
}

// ---------------- launch ----------------

extern "C" void kernel_launch(void* const* d_in, const int* in_sizes, int n_in,
                              void* d_out, int out_size, void* d_ws, size_t ws_size,
                              hipStream_t stream) {
  const float* x        = (const float*)d_in[0];
  const float* W_hidden = (const float*)d_in[1];
  const float* b_hidden = (const float*)d_in[2];
  const float* W_qk     = (const float*)d_in[3];
  const float* b_qk     = (const float*)d_in[4];
  const float* gamma    = (const float*)d_in[5];
  const float* beta     = (const float*)d_in[6];
  const float* W_out    = (const float*)d_in[7];
  const float* b_out    = (const float*)d_in[8];
  float* out = (float*)d_out;

  const bool fullM = ws_size >= (236ull << 20);
  const size_t region0 = fullM ? (128ull << 20) : (64ull << 20);

  char* base = (char*)d_ws;
  uint16_t* xb    = (uint16_t*)(base);                         // 16 MB  [8192][1024]
  uint16_t* WhT   = (uint16_t*)(base + (16ull << 20));         //  8 MB  [4096][1024]
  uint16_t* WqkT  = (uint16_t*)(base + (24ull << 20));         // .5 MB  [256][1024] (contiguous after WhT!)
  uint16_t* attnB = (uint16_t*)(base);                         // 64/128 MB (aliases the above)
  char* tail = base + region0;
  uint16_t* WoT   = (uint16_t*)(tail);                         //  4 MB  [1024][2048]
  uint16_t* q     = (uint16_t*)(tail + (4ull << 20));          // 3.5 MB [8192][224]
  uint16_t* kk    = (uint16_t*)(tail + (4ull << 20) + 3670016);// 3.5 MB
  uint16_t* vT    = (uint16_t*)(tail + (4ull << 20) + 2 * 3670016);                  // 32 MB [2048][8192]
  uint16_t* gate  = (uint16_t*)(tail + (4ull << 20) + 2 * 3670016 + (32ull << 20));  // 32 MB
  uint16_t* out2g = (uint16_t*)(tail + (4ull << 20) + 2 * 3670016 + (64ull << 20));  // 32 MB
  (void)in_sizes; (void)n_in; (void)out_size;

  // prep
  cast_to_bf16<<<(8192 * 1024 / 4) / 256, 256, 0, stream>>>(x, xb, 8192 * 1024 / 4);
  transpose_cast_pad<<<dim3(4096 / 32, 1024 / 32), dim3(32, 8), 0, stream>>>(W_hidden, WhT, 1024, 4096, 4096);
  transpose_cast_pad<<<dim3(256 / 32, 1024 / 32), dim3(32, 8), 0, stream>>>(W_qk, WqkT, 1024, 200, 256);
  transpose_cast_pad<<<dim3(1024 / 32, 2048 / 32), dim3(32, 8), 0, stream>>>(W_out, WoT, 2048, 1024, 1024);

  // fused: hid (vT,gate) + qk (q,k)    N=4352, grid 34x64
  {
    EpiParams p{};
    p.bias = b_hidden; p.bias2 = b_qk;
    p.g0 = gamma; p.b0 = beta; p.g1 = gamma + 200; p.b1 = beta + 200;
    p.o16a = vT; p.o16b = gate; p.oq = q; p.ok = kk;
    k_fused_hid_qk<<<dim3(34, 64), 256, 0, stream>>>(xb, WhT, p);
  }

  if (fullM) {
    {
      EpiParams p{};
      p.o16a = attnB;
      k_attn<<<dim3(64, 64), 256, 0, stream>>>(q, kk, p);
    }
    {
      EpiParams p{};
      p.gate = gate; p.o16a = out2g;
      k_pv<<<dim3(8 * 64), 512, 0, stream>>>(attnB, 8192, vT, 8192, 8192, 8, p);
    }
  } else {
    for (int s = 0; s < 2; ++s) {
      {
        EpiParams p{};
        p.o16a = attnB;
        k_attn<<<dim3(64, 32), 256, 0, stream>>>(q + (size_t)s * 4096 * 224, kk, p);
      }
      {
        EpiParams p{};
        p.gate = gate + (size_t)s * 4096 * 2048;
        p.o16a = out2g + (size_t)s * 4096 * 2048;
        k_pv<<<dim3(8 * 32), 512, 0, stream>>>(attnB, 8192, vT, 8192, 8192, 8, p);
      }
    }
  }

  // y = (out2g@Wo + bo) * x
  {
    EpiParams p{};
    p.bias = b_out; p.x = x; p.o32 = out;
    k_final<<<dim3(8, 64), 256, 0, stream>>>(out2g, WoT, p);
  }
}